// Round 2
// baseline (91776.318 us; speedup 1.0000x reference)
//
#include <hip/hip_runtime.h>
#include <stdint.h>

// TLSTM: batch-1 LSTM, T=16384 steps, IN=512, H=1024, OUT=64.
// Persistent-kernel design: 256 WGs (one per CU). WG b owns h-elements
// {4b..4b+3}; wave w owns element 4b+w and computes all 4 gate rows for
// it; weights live in registers. Cross-WG h exchange per step through a
// tagged word per h-element in d_ws, double-buffered by step parity.
//
// R2 changes:
//  (a) 4B exchange words: tag = (step & 3) packed into the low 2 mantissa
//      bits of the fp32 h value. The slot at a given parity can only hold
//      step t or stale step t-2 (skew bounded to 1 by the all-to-all
//      dependency), so 2 bits distinguish them. Perturbation ~2^-23 rel.
//      Poll footprint halves: 4KB / 64 lines per WG-sweep, 1 dwordx4 per
//      thread per sweep.
//  (b) Pipelined 2-slot poll: two loads always in flight, counted
//      s_waitcnt vmcnt(1) -> sampling period halves, detect ~0.75 RTT.
//      Register data-deps ("+v") on the waitcnt asm stop the compiler
//      hoisting checks above the waits.
//  (c) x-projection in registers, prefetched one row ahead; per-lane x
//      partials computed BEFORE the barrier; x_lds removed.

typedef uint32_t u32;
typedef uint32_t u32x4 __attribute__((ext_vector_type(4)));

#define T_STEPS 16384
#define IN_DIM  512
#define H_DIM   1024
#define OUT_DIM 64
#define NWG     256

__device__ __forceinline__ float sigf(float x) {
    return 1.0f / (1.0f + __expf(-x));
}
__device__ __forceinline__ float tanh_fast(float x) {
    return 2.0f / (1.0f + __expf(-2.0f * x)) - 1.0f;
}

// One LSTM step. XC0/XC1: this step's x chunks (in regs, already issued;
// validated by the vmcnt(0) drain after the poll). XN0/XN1: regs to
// prefetch next row into (issued after the barrier so the compiler's
// pre-barrier drain never waits on them).
#define STEP(T_, XC0, XC1, XN0, XN1) do {                                     \
    const int   p_   = (T_) & 1;                                              \
    const u32   tu_  = (u32)(T_) & 3u;                                        \
    const u32*  src_ = p_ ? poll1 : poll0;                                    \
    asm volatile("global_load_dwordx4 %0, %2, off sc0 sc1\n\t"                \
                 "global_load_dwordx4 %1, %2, off sc0 sc1"                    \
                 : "=&v"(A), "=&v"(B) : "v"(src_) : "memory");                \
    for (;;) {                                                                \
        asm volatile("s_waitcnt vmcnt(1)" : "+v"(A) :: "memory");             \
        if (((((A[0]^tu_)|(A[1]^tu_))|((A[2]^tu_)|(A[3]^tu_))) & 3u) == 0u) { \
            got = A; break;                                                   \
        }                                                                     \
        asm volatile("global_load_dwordx4 %0, %1, off sc0 sc1"                \
                     : "=&v"(A) : "v"(src_) : "memory");                      \
        asm volatile("s_waitcnt vmcnt(1)" : "+v"(B) :: "memory");             \
        if (((((B[0]^tu_)|(B[1]^tu_))|((B[2]^tu_)|(B[3]^tu_))) & 3u) == 0u) { \
            got = B; break;                                                   \
        }                                                                     \
        asm volatile("global_load_dwordx4 %0, %1, off sc0 sc1"                \
                     : "=&v"(B) : "v"(src_) : "memory");                      \
    }                                                                         \
    /* drain stragglers; also orders XC consumption after load completion */  \
    asm volatile("s_waitcnt vmcnt(0)"                                         \
                 : "+v"(A), "+v"(B), "+v"(XC0), "+v"(XC1) :: "memory");       \
    *(u32x4*)(&h_lds[p_][tid * 4]) = got;                                     \
    float a0_, a1_, a2_, a3_;                                                 \
    {                                                                         \
        const float x0_=__uint_as_float(XC0[0]), x1_=__uint_as_float(XC0[1]); \
        const float x2_=__uint_as_float(XC0[2]), x3_=__uint_as_float(XC0[3]); \
        const float y0_=__uint_as_float(XC1[0]), y1_=__uint_as_float(XC1[1]); \
        const float y2_=__uint_as_float(XC1[2]), y3_=__uint_as_float(XC1[3]); \
        a0_ = wx[0][0].x*x0_ + wx[0][0].y*x1_ + wx[0][0].z*x2_ + wx[0][0].w*x3_ \
            + wx[0][1].x*y0_ + wx[0][1].y*y1_ + wx[0][1].z*y2_ + wx[0][1].w*y3_; \
        a1_ = wx[1][0].x*x0_ + wx[1][0].y*x1_ + wx[1][0].z*x2_ + wx[1][0].w*x3_ \
            + wx[1][1].x*y0_ + wx[1][1].y*y1_ + wx[1][1].z*y2_ + wx[1][1].w*y3_; \
        a2_ = wx[2][0].x*x0_ + wx[2][0].y*x1_ + wx[2][0].z*x2_ + wx[2][0].w*x3_ \
            + wx[2][1].x*y0_ + wx[2][1].y*y1_ + wx[2][1].z*y2_ + wx[2][1].w*y3_; \
        a3_ = wx[3][0].x*x0_ + wx[3][0].y*x1_ + wx[3][0].z*x2_ + wx[3][0].w*x3_ \
            + wx[3][1].x*y0_ + wx[3][1].y*y1_ + wx[3][1].z*y2_ + wx[3][1].w*y3_; \
    }                                                                         \
    __syncthreads();                                                          \
    {                                                                         \
        const int nr_ = ((T_) + 1 < T_STEPS) ? (T_) + 1 : (T_STEPS - 1);      \
        const float* xp_ = X + (size_t)nr_ * IN_DIM + lane * 4;               \
        asm volatile("global_load_dwordx4 %0, %2, off\n\t"                    \
                     "global_load_dwordx4 %1, %3, off"                        \
                     : "=&v"(XN0), "=&v"(XN1)                                 \
                     : "v"(xp_), "v"(xp_ + 256) : "memory");                  \
    }                                                                         \
    const float4* h4_ = (const float4*)(&h_lds[p_][0]);                       \
    _Pragma("unroll")                                                         \
    for (int c = 0; c < 4; ++c) {                                             \
        const float4 hv = h4_[c * 64 + lane];                                 \
        a0_ += wh[0][c].x*hv.x + wh[0][c].y*hv.y + wh[0][c].z*hv.z + wh[0][c].w*hv.w; \
        a1_ += wh[1][c].x*hv.x + wh[1][c].y*hv.y + wh[1][c].z*hv.z + wh[1][c].w*hv.w; \
        a2_ += wh[2][c].x*hv.x + wh[2][c].y*hv.y + wh[2][c].z*hv.z + wh[2][c].w*hv.w; \
        a3_ += wh[3][c].x*hv.x + wh[3][c].y*hv.y + wh[3][c].z*hv.z + wh[3][c].w*hv.w; \
    }                                                                         \
    _Pragma("unroll")                                                         \
    for (int off_ = 32; off_ >= 1; off_ >>= 1) {                              \
        a0_ += __shfl_xor(a0_, off_); a1_ += __shfl_xor(a1_, off_);           \
        a2_ += __shfl_xor(a2_, off_); a3_ += __shfl_xor(a3_, off_);           \
    }                                                                         \
    const float ii_ = sigf(a0_ + bias_g[0]);                                  \
    const float ff_ = sigf(a1_ + bias_g[1]);                                  \
    const float gg_ = tanh_fast(a2_ + bias_g[2]);                             \
    const float oo_ = sigf(a3_ + bias_g[3]);                                  \
    const float cn_ = ff_ * c_state + ii_ * gg_;                              \
    c_state = cn_;                                                            \
    const float hn_ = oo_ * tanh_fast(cn_);                                   \
    if (lane == 0) {                                                          \
        const u32 word_ = (__float_as_uint(hn_) & ~3u) | ((u32)((T_) + 1) & 3u); \
        __hip_atomic_store(hbuf + (size_t)(((T_) + 1) & 1) * H_DIM + elem,    \
                           word_, __ATOMIC_RELAXED, __HIP_MEMORY_SCOPE_AGENT);\
    }                                                                         \
} while (0)

__global__ __launch_bounds__(256, 1) void lstm_seq(
    const float* __restrict__ X,
    const float* __restrict__ W_ih,
    const float* __restrict__ W_hh,
    const float* __restrict__ b_ih,
    const float* __restrict__ b_hh,
    u32* __restrict__ hbuf)   // [2][H_DIM] 4B tagged words in d_ws
{
    const int b    = blockIdx.x;      // 0..255
    const int tid  = threadIdx.x;     // 0..255
    const int w    = tid >> 6;        // wave id == owned element index j
    const int lane = tid & 63;
    const int elem = 4 * b + w;       // global h index this wave produces

    __shared__ float h_lds[2][H_DIM];

    // ---- one-time: weights into registers ----
    float4 wh[4][4];   // [gate][chunk]  over H_DIM=1024
    float4 wx[4][2];   // [gate][chunk]  over IN_DIM=512
    float  bias_g[4];
    #pragma unroll
    for (int g = 0; g < 4; ++g) {
        const int row = g * H_DIM + elem;
        #pragma unroll
        for (int c = 0; c < 4; ++c)
            wh[g][c] = *(const float4*)(W_hh + (size_t)row * H_DIM + (c * 256 + lane * 4));
        #pragma unroll
        for (int c = 0; c < 2; ++c)
            wx[g][c] = *(const float4*)(W_ih + (size_t)row * IN_DIM + (c * 256 + lane * 4));
        bias_g[g] = b_ih[row] + b_hh[row];
    }
    // Force the compiler's counted waits for the weight loads to resolve
    // HERE, not inside the loop where our asm loads skew its vmcnt model.
    {
        float wsum = bias_g[0] + bias_g[1] + bias_g[2] + bias_g[3];
        #pragma unroll
        for (int g = 0; g < 4; ++g) {
            #pragma unroll
            for (int c = 0; c < 4; ++c)
                wsum += wh[g][c].x + wh[g][c].y + wh[g][c].z + wh[g][c].w;
            #pragma unroll
            for (int c = 0; c < 2; ++c)
                wsum += wx[g][c].x + wx[g][c].y + wx[g][c].z + wx[g][c].w;
        }
        asm volatile("" :: "v"(wsum));
    }

    // per-thread poll bases (4 tagged words = 16B per thread)
    const u32* poll0 = hbuf + (size_t)tid * 4;
    const u32* poll1 = hbuf + (size_t)H_DIM + (size_t)tid * 4;

    // x prefetch: row 0 into xA
    u32x4 xA0, xA1, xB0, xB1;
    {
        const float* xp = X + lane * 4;
        asm volatile("global_load_dwordx4 %0, %2, off\n\t"
                     "global_load_dwordx4 %1, %3, off"
                     : "=&v"(xA0), "=&v"(xA1)
                     : "v"(xp), "v"(xp + 256) : "memory");
    }

    float c_state = 0.0f;
    u32x4 A, B, got;

    for (int t = 0; t < T_STEPS; t += 2) {
        STEP(t,     xA0, xA1, xB0, xB1);
        STEP(t + 1, xB0, xB1, xA0, xA1);
    }
}

__global__ __launch_bounds__(256, 1) void lstm_head(
    const float* __restrict__ hbuf,
    const float* __restrict__ W_lin,
    const float* __restrict__ b_lin,
    float* __restrict__ out)
{
    const int tid  = threadIdx.x;
    const int o    = tid >> 2;       // output index, 4 threads per output
    const int part = tid & 3;
    const float* src = hbuf + (size_t)(T_STEPS & 1) * H_DIM;  // buf[0]: tag T&3

    float sum = 0.f;
    const int k0 = part * 256;
    for (int k = k0; k < k0 + 256; k += 4) {
        const float4 wv = *(const float4*)(W_lin + (size_t)o * H_DIM + k);
        sum += wv.x * src[k + 0] + wv.y * src[k + 1]
             + wv.z * src[k + 2] + wv.w * src[k + 3];
    }
    sum += __shfl_xor(sum, 1);
    sum += __shfl_xor(sum, 2);
    if (part == 0)
        out[o] = 1.0f / (1.0f + __expf(-(sum + b_lin[o])));
}

extern "C" void kernel_launch(void* const* d_in, const int* in_sizes, int n_in,
                              void* d_out, int out_size, void* d_ws, size_t ws_size,
                              hipStream_t stream) {
    const float* X     = (const float*)d_in[0];
    // d_in[1] Mask, d_in[2] Delta, d_in[3] dt: unused by the forward pass
    const float* W_ih  = (const float*)d_in[4];
    const float* W_hh  = (const float*)d_in[5];
    const float* b_ih  = (const float*)d_in[6];
    const float* b_hh  = (const float*)d_in[7];
    const float* W_lin = (const float*)d_in[8];
    const float* b_lin = (const float*)d_in[9];
    float* out = (float*)d_out;

    u32* hbuf = (u32*)d_ws;   // 2 * 1024 * 4B = 8 KiB used

    // init: both parity buffers = {tag=0, h=0.0f} (all zero bytes)
    hipMemsetAsync(hbuf, 0, 2 * H_DIM * sizeof(u32), stream);

    lstm_seq<<<NWG, 256, 0, stream>>>(X, W_ih, W_hh, b_ih, b_hh, hbuf);
    lstm_head<<<1, 256, 0, stream>>>((const float*)hbuf, W_lin, b_lin, out);
}

// Round 3
// 36851.666 us; speedup vs baseline: 2.4904x; 2.4904x over previous
//
#include <hip/hip_runtime.h>
#include <stdint.h>

// TLSTM: batch-1 LSTM, T=16384 steps, IN=512, H=1024, OUT=64.
// Persistent-kernel design: 256 WGs (one per CU). WG b owns h-elements
// {4b..4b+3}; wave w owns element 4b+w and computes all 4 gate rows for
// it; weights live in registers (96 floats/lane, loaded once). Cross-WG
// h exchange per step through one tagged 4B word per h-element in d_ws,
// double-buffered by step parity.
//
// R3 = R1 structure (verified 29.0 ms) + 4B tagged words (verified
// correct in R2). R2's pipelined counted-vmcnt poll is REVERTED: it
// doubled ungated device-scope load pressure at the coherence point
// (starving producer stores -> visibility latency spiral, 3-4x slower,
// high variance) while its two in-flight loads sampled the same epoch
// (no sampling-rate gain). Lesson: this design is PRESSURE-limited.
//
// 4B word: tag = (step & 3) packed into the low 2 mantissa bits of the
// fp32 h value. A parity slot only ever holds step t or stale t-2 (skew
// is bounded to 1 step by the all-to-all dependency), and those tags
// differ in bit 1, so 2 bits suffice. Value perturbation ~2^-23 rel
// (empirically absmax stays 0.0). Poll footprint per WG-sweep: 4 KB /
// 64 lines, one dwordx4 per thread; producer store is 4B.

typedef uint32_t u32;
typedef uint32_t u32x4 __attribute__((ext_vector_type(4)));

#define T_STEPS 16384
#define IN_DIM  512
#define H_DIM   1024
#define OUT_DIM 64
#define NWG     256

__device__ __forceinline__ float sigf(float x) {
    return 1.0f / (1.0f + __expf(-x));
}
__device__ __forceinline__ float tanh_fast(float x) {
    // tanh(x) = 2*sigmoid(2x) - 1 ; |err| ~1e-7 rel with __expf
    return 2.0f / (1.0f + __expf(-2.0f * x)) - 1.0f;
}

__global__ __launch_bounds__(256, 1) void lstm_seq(
    const float* __restrict__ X,
    const float* __restrict__ W_ih,
    const float* __restrict__ W_hh,
    const float* __restrict__ b_ih,
    const float* __restrict__ b_hh,
    u32* __restrict__ hbuf)   // [2][H_DIM] 4B tagged words in d_ws
{
    const int b    = blockIdx.x;      // 0..255
    const int tid  = threadIdx.x;     // 0..255
    const int w    = tid >> 6;        // wave id == owned element index j
    const int lane = tid & 63;
    const int elem = 4 * b + w;       // global h index this wave produces

    __shared__ float h_lds[2][H_DIM];
    __shared__ float x_lds[2][IN_DIM];

    // ---- one-time: weights into registers ----
    // lane covers k = c*256 + lane*4 + {0..3}  (contiguous float4, coalesced
    // global loads and conflict-free ds_read_b128 later).
    float4 wh[4][4];   // [gate][chunk]  over H_DIM=1024
    float4 wx[4][2];   // [gate][chunk]  over IN_DIM=512
    float  bias_g[4];
    #pragma unroll
    for (int g = 0; g < 4; ++g) {
        const int row = g * H_DIM + elem;
        #pragma unroll
        for (int c = 0; c < 4; ++c)
            wh[g][c] = *(const float4*)(W_hh + (size_t)row * H_DIM + (c * 256 + lane * 4));
        #pragma unroll
        for (int c = 0; c < 2; ++c)
            wx[g][c] = *(const float4*)(W_ih + (size_t)row * IN_DIM + (c * 256 + lane * 4));
        bias_g[g] = b_ih[row] + b_hh[row];
    }

    // per-thread poll bases for the two parity buffers (4 words = 16B)
    const u32* poll0 = hbuf + (size_t)tid * 4;
    const u32* poll1 = hbuf + (size_t)H_DIM + (size_t)tid * 4;

    float c_state = 0.0f;   // cell state for `elem` (consistent across lanes)

    for (int t = 0; t < T_STEPS; ++t) {
        const int p = t & 1;

        // ---- stage x[t] into LDS (issue global load before the spin) ----
        const float2 xv = *(const float2*)(X + (size_t)t * IN_DIM + tid * 2);
        *(float2*)(&x_lds[p][tid * 2]) = xv;

        // ---- poll h[t]: 4 tagged words per thread, one 16B cache-bypass
        //      load per sweep; serial vmcnt(0) gates the sweep rate ----
        {
            const u32* src = p ? poll1 : poll0;
            const u32 tu = (u32)t & 3u;
            u32x4 a;
            for (;;) {
                asm volatile("global_load_dwordx4 %0, %1, off sc0 sc1\n\t"
                             "s_waitcnt vmcnt(0)"
                             : "=&v"(a) : "v"(src) : "memory");
                if (((((a[0] ^ tu) | (a[1] ^ tu)) |
                      ((a[2] ^ tu) | (a[3] ^ tu))) & 3u) == 0u)
                    break;
            }
            // store with tags embedded (perturbation ~2^-23 rel)
            *(u32x4*)(&h_lds[p][tid * 4]) = a;
        }
        __syncthreads();   // single barrier per step: staging complete

        // ---- 4 gate dot-products for `elem` ----
        float acc0 = 0.f, acc1 = 0.f, acc2 = 0.f, acc3 = 0.f;
        const float4* h4 = (const float4*)(&h_lds[p][0]);
        const float4* x4 = (const float4*)(&x_lds[p][0]);
        #pragma unroll
        for (int c = 0; c < 4; ++c) {
            const float4 hv = h4[c * 64 + lane];
            acc0 += wh[0][c].x*hv.x + wh[0][c].y*hv.y + wh[0][c].z*hv.z + wh[0][c].w*hv.w;
            acc1 += wh[1][c].x*hv.x + wh[1][c].y*hv.y + wh[1][c].z*hv.z + wh[1][c].w*hv.w;
            acc2 += wh[2][c].x*hv.x + wh[2][c].y*hv.y + wh[2][c].z*hv.z + wh[2][c].w*hv.w;
            acc3 += wh[3][c].x*hv.x + wh[3][c].y*hv.y + wh[3][c].z*hv.z + wh[3][c].w*hv.w;
        }
        #pragma unroll
        for (int c = 0; c < 2; ++c) {
            const float4 qv = x4[c * 64 + lane];
            acc0 += wx[0][c].x*qv.x + wx[0][c].y*qv.y + wx[0][c].z*qv.z + wx[0][c].w*qv.w;
            acc1 += wx[1][c].x*qv.x + wx[1][c].y*qv.y + wx[1][c].z*qv.z + wx[1][c].w*qv.w;
            acc2 += wx[2][c].x*qv.x + wx[2][c].y*qv.y + wx[2][c].z*qv.z + wx[2][c].w*qv.w;
            acc3 += wx[3][c].x*qv.x + wx[3][c].y*qv.y + wx[3][c].z*qv.z + wx[3][c].w*qv.w;
        }

        // ---- full-wave butterfly reduce (all lanes end with the sums) ----
        #pragma unroll
        for (int off = 32; off >= 1; off >>= 1) {
            acc0 += __shfl_xor(acc0, off);
            acc1 += __shfl_xor(acc1, off);
            acc2 += __shfl_xor(acc2, off);
            acc3 += __shfl_xor(acc3, off);
        }

        // ---- combine (all lanes compute; avoids divergent exec region) ----
        const float ii = sigf(acc0 + bias_g[0]);
        const float ff = sigf(acc1 + bias_g[1]);
        const float gg = tanh_fast(acc2 + bias_g[2]);
        const float oo = sigf(acc3 + bias_g[3]);
        const float cn = ff * c_state + ii * gg;
        c_state = cn;
        const float hn = oo * tanh_fast(cn);

        if (lane == 0) {
            const u32 word = (__float_as_uint(hn) & ~3u) | ((u32)(t + 1) & 3u);
            __hip_atomic_store(hbuf + (size_t)((t + 1) & 1) * H_DIM + elem,
                               word, __ATOMIC_RELAXED, __HIP_MEMORY_SCOPE_AGENT);
        }
        // No second barrier needed: next-step staging writes parity (t+1)&1,
        // disjoint from this step's reads; tag protocol covers parity reuse.
    }
}

__global__ __launch_bounds__(256, 1) void lstm_head(
    const float* __restrict__ hbuf,
    const float* __restrict__ W_lin,
    const float* __restrict__ b_lin,
    float* __restrict__ out)
{
    const int tid  = threadIdx.x;
    const int o    = tid >> 2;       // output index, 4 threads per output
    const int part = tid & 3;
    const float* src = hbuf + (size_t)(T_STEPS & 1) * H_DIM;  // buf[0]: h_T

    float sum = 0.f;
    const int k0 = part * 256;
    for (int k = k0; k < k0 + 256; k += 4) {
        const float4 wv = *(const float4*)(W_lin + (size_t)o * H_DIM + k);
        sum += wv.x * src[k + 0] + wv.y * src[k + 1]
             + wv.z * src[k + 2] + wv.w * src[k + 3];
    }
    sum += __shfl_xor(sum, 1);
    sum += __shfl_xor(sum, 2);
    if (part == 0)
        out[o] = 1.0f / (1.0f + __expf(-(sum + b_lin[o])));
}

extern "C" void kernel_launch(void* const* d_in, const int* in_sizes, int n_in,
                              void* d_out, int out_size, void* d_ws, size_t ws_size,
                              hipStream_t stream) {
    const float* X     = (const float*)d_in[0];
    // d_in[1] Mask, d_in[2] Delta, d_in[3] dt: unused by the forward pass
    const float* W_ih  = (const float*)d_in[4];
    const float* W_hh  = (const float*)d_in[5];
    const float* b_ih  = (const float*)d_in[6];
    const float* b_hh  = (const float*)d_in[7];
    const float* W_lin = (const float*)d_in[8];
    const float* b_lin = (const float*)d_in[9];
    float* out = (float*)d_out;

    u32* hbuf = (u32*)d_ws;   // 2 * 1024 * 4B = 8 KiB used

    // init: both parity buffers = {tag=0, h=0.0f} (all zero bytes)
    hipMemsetAsync(hbuf, 0, 2 * H_DIM * sizeof(u32), stream);

    lstm_seq<<<NWG, 256, 0, stream>>>(X, W_ih, W_hh, b_ih, b_hh, hbuf);
    lstm_head<<<1, 256, 0, stream>>>((const float*)hbuf, W_lin, b_lin, out);
}

// Round 4
// 29021.506 us; speedup vs baseline: 3.1624x; 1.2698x over previous
//
#include <hip/hip_runtime.h>
#include <stdint.h>

// TLSTM: batch-1 LSTM, T=16384 steps, IN=512, H=1024, OUT=64.
// Persistent-kernel design: 256 WGs (one per CU). WG b owns h-elements
// {4b..4b+3}; wave w owns element 4b+w and computes all 4 gate rows for
// it; weights live in registers (96 floats/lane, loaded once). Cross-WG
// exchange of h each step through a tagged 64-bit {step, value} word per
// h-element in d_ws, double-buffered by step parity.
//
// R4 = exact R1 structure (verified 29.0 ms) + s_sleep-paced polling.
// History of the exchange-path experiments:
//   R1: coalesced 2x16B poll sweeps (was 4x strided 8B)      -> 35->29 ms
//   R2: pipelined counted-vmcnt poll (2 ungated in-flight)   -> 90+ ms
//       (doubled device-scope load pressure, starved stores)
//   R3: 4B tagged words (footprint 16KB->8KB, 4B stores)     -> 36.5 ms
//       (hot set compacted onto half the L3 lines/channels; more
//        producer WGs false-sharing each line)
// Lessons: layout spread is GOOD (keep 8B words / 16 KB), request RATE
// is the enemy. R4 paces the poll: sleep ~128cy before the first sample
// (producers stored ~0cy ago; an immediate sample cannot hit) and ~128cy
// between samples. Expected sweeps/step ~5 -> ~2, and producer stores
// see empty L3 queues during sleep windows -> faster visibility.

typedef unsigned long long u64;
typedef uint32_t u32x4 __attribute__((ext_vector_type(4)));

#define T_STEPS 16384
#define IN_DIM  512
#define H_DIM   1024
#define OUT_DIM 64
#define NWG     256

__device__ __forceinline__ float sigf(float x) {
    return 1.0f / (1.0f + __expf(-x));
}
__device__ __forceinline__ float tanh_fast(float x) {
    // tanh(x) = 2*sigmoid(2x) - 1 ; |err| ~1e-7 rel with __expf
    return 2.0f / (1.0f + __expf(-2.0f * x)) - 1.0f;
}

__global__ __launch_bounds__(256, 1) void lstm_seq(
    const float* __restrict__ X,
    const float* __restrict__ W_ih,
    const float* __restrict__ W_hh,
    const float* __restrict__ b_ih,
    const float* __restrict__ b_hh,
    u64* __restrict__ hbuf)   // [2][H_DIM] tagged words in d_ws
{
    const int b    = blockIdx.x;      // 0..255
    const int tid  = threadIdx.x;     // 0..255
    const int w    = tid >> 6;        // wave id == owned element index j
    const int lane = tid & 63;
    const int elem = 4 * b + w;       // global h index this wave produces

    __shared__ float h_lds[2][H_DIM];
    __shared__ float x_lds[2][IN_DIM];

    // ---- one-time: weights into registers ----
    // lane covers k = c*256 + lane*4 + {0..3}  (contiguous float4, coalesced
    // global loads and conflict-free ds_read_b128 later).
    float4 wh[4][4];   // [gate][chunk]  over H_DIM=1024
    float4 wx[4][2];   // [gate][chunk]  over IN_DIM=512
    float  bias_g[4];
    #pragma unroll
    for (int g = 0; g < 4; ++g) {
        const int row = g * H_DIM + elem;
        #pragma unroll
        for (int c = 0; c < 4; ++c)
            wh[g][c] = *(const float4*)(W_hh + (size_t)row * H_DIM + (c * 256 + lane * 4));
        #pragma unroll
        for (int c = 0; c < 2; ++c)
            wx[g][c] = *(const float4*)(W_ih + (size_t)row * IN_DIM + (c * 256 + lane * 4));
        bias_g[g] = b_ih[row] + b_hh[row];
    }

    // per-thread poll bases for the two parity buffers (4 tagged words = 32B)
    const uint32_t* poll0 = (const uint32_t*)(hbuf + (size_t)tid * 4);
    const uint32_t* poll1 = (const uint32_t*)(hbuf + (size_t)H_DIM + (size_t)tid * 4);

    float c_state = 0.0f;   // cell state for `elem` (consistent across lanes)

    for (int t = 0; t < T_STEPS; ++t) {
        const int p = t & 1;

        // ---- stage x[t] into LDS (issue global load before the spin) ----
        const float2 xv = *(const float2*)(X + (size_t)t * IN_DIM + tid * 2);
        *(float2*)(&x_lds[p][tid * 2]) = xv;

        // ---- poll h[t]: 4 tagged words per thread, coalesced 2x16B reads,
        //      s_sleep-paced (see header) ----
        {
            const uint32_t* src = p ? poll1 : poll0;
            const uint32_t tu = (uint32_t)t;
            u32x4 a, b4;
            __builtin_amdgcn_s_sleep(2);   // producers stored ~now; first
                                           // immediate sample cannot hit
            for (;;) {
                asm volatile(
                    "global_load_dwordx4 %0, %2, off sc0 sc1\n\t"
                    "global_load_dwordx4 %1, %2, off offset:16 sc0 sc1\n\t"
                    "s_waitcnt vmcnt(0)"
                    : "=&v"(a), "=&v"(b4)
                    : "v"(src)
                    : "memory");
                // dwords: [val0, tag0, val1, tag1]
                if ((((a[1] ^ tu) | (a[3] ^ tu)) | ((b4[1] ^ tu) | (b4[3] ^ tu))) == 0u)
                    break;
                __builtin_amdgcn_s_sleep(2);   // pace retries: keep L3 queues
                                               // clear for producer stores
            }
            h_lds[p][tid * 4 + 0] = __uint_as_float(a[0]);
            h_lds[p][tid * 4 + 1] = __uint_as_float(a[2]);
            h_lds[p][tid * 4 + 2] = __uint_as_float(b4[0]);
            h_lds[p][tid * 4 + 3] = __uint_as_float(b4[2]);
        }
        __syncthreads();   // single barrier per step: staging complete

        // ---- 4 gate dot-products for `elem` ----
        float acc0 = 0.f, acc1 = 0.f, acc2 = 0.f, acc3 = 0.f;
        const float4* h4 = (const float4*)(&h_lds[p][0]);
        const float4* x4 = (const float4*)(&x_lds[p][0]);
        #pragma unroll
        for (int c = 0; c < 4; ++c) {
            const float4 hv = h4[c * 64 + lane];
            acc0 += wh[0][c].x*hv.x + wh[0][c].y*hv.y + wh[0][c].z*hv.z + wh[0][c].w*hv.w;
            acc1 += wh[1][c].x*hv.x + wh[1][c].y*hv.y + wh[1][c].z*hv.z + wh[1][c].w*hv.w;
            acc2 += wh[2][c].x*hv.x + wh[2][c].y*hv.y + wh[2][c].z*hv.z + wh[2][c].w*hv.w;
            acc3 += wh[3][c].x*hv.x + wh[3][c].y*hv.y + wh[3][c].z*hv.z + wh[3][c].w*hv.w;
        }
        #pragma unroll
        for (int c = 0; c < 2; ++c) {
            const float4 qv = x4[c * 64 + lane];
            acc0 += wx[0][c].x*qv.x + wx[0][c].y*qv.y + wx[0][c].z*qv.z + wx[0][c].w*qv.w;
            acc1 += wx[1][c].x*qv.x + wx[1][c].y*qv.y + wx[1][c].z*qv.z + wx[1][c].w*qv.w;
            acc2 += wx[2][c].x*qv.x + wx[2][c].y*qv.y + wx[2][c].z*qv.z + wx[2][c].w*qv.w;
            acc3 += wx[3][c].x*qv.x + wx[3][c].y*qv.y + wx[3][c].z*qv.z + wx[3][c].w*qv.w;
        }

        // ---- full-wave butterfly reduce (all lanes end with the sums) ----
        #pragma unroll
        for (int off = 32; off >= 1; off >>= 1) {
            acc0 += __shfl_xor(acc0, off);
            acc1 += __shfl_xor(acc1, off);
            acc2 += __shfl_xor(acc2, off);
            acc3 += __shfl_xor(acc3, off);
        }

        // ---- combine (all lanes compute; avoids divergent exec region) ----
        const float ii = sigf(acc0 + bias_g[0]);
        const float ff = sigf(acc1 + bias_g[1]);
        const float gg = tanh_fast(acc2 + bias_g[2]);
        const float oo = sigf(acc3 + bias_g[3]);
        const float cn = ff * c_state + ii * gg;
        c_state = cn;
        const float hn = oo * tanh_fast(cn);

        if (lane == 0) {
            const u64 word = ((u64)(unsigned)(t + 1) << 32)
                           | (u64)__float_as_uint(hn);
            __hip_atomic_store(hbuf + (size_t)((t + 1) & 1) * H_DIM + elem,
                               word, __ATOMIC_RELAXED, __HIP_MEMORY_SCOPE_AGENT);
        }
        // No second barrier needed: next-step staging writes parity (t+1)&1,
        // disjoint from this step's reads; tag protocol covers parity reuse.
    }
}

__global__ __launch_bounds__(256, 1) void lstm_head(
    const u64* __restrict__ hbuf,
    const float* __restrict__ W_lin,
    const float* __restrict__ b_lin,
    float* __restrict__ out)
{
    const int tid  = threadIdx.x;
    const int o    = tid >> 2;       // output index, 4 threads per output
    const int part = tid & 3;
    const u64* src = hbuf + (size_t)(T_STEPS & 1) * H_DIM;  // buf[0]: tag T

    float sum = 0.f;
    const int k0 = part * 256;
    for (int k = k0; k < k0 + 256; k += 4) {
        const float4 wv = *(const float4*)(W_lin + (size_t)o * H_DIM + k);
        sum += wv.x * __uint_as_float((unsigned)src[k + 0])
             + wv.y * __uint_as_float((unsigned)src[k + 1])
             + wv.z * __uint_as_float((unsigned)src[k + 2])
             + wv.w * __uint_as_float((unsigned)src[k + 3]);
    }
    sum += __shfl_xor(sum, 1);
    sum += __shfl_xor(sum, 2);
    if (part == 0)
        out[o] = 1.0f / (1.0f + __expf(-(sum + b_lin[o])));
}

extern "C" void kernel_launch(void* const* d_in, const int* in_sizes, int n_in,
                              void* d_out, int out_size, void* d_ws, size_t ws_size,
                              hipStream_t stream) {
    const float* X     = (const float*)d_in[0];
    // d_in[1] Mask, d_in[2] Delta, d_in[3] dt: unused by the forward pass
    const float* W_ih  = (const float*)d_in[4];
    const float* W_hh  = (const float*)d_in[5];
    const float* b_ih  = (const float*)d_in[6];
    const float* b_hh  = (const float*)d_in[7];
    const float* W_lin = (const float*)d_in[8];
    const float* b_lin = (const float*)d_in[9];
    float* out = (float*)d_out;

    u64* hbuf = (u64*)d_ws;   // 2 * 1024 * 8B = 16 KiB used

    // init: both parity buffers = {tag=0, h=0.0f} (all zero bytes)
    hipMemsetAsync(hbuf, 0, 2 * H_DIM * sizeof(u64), stream);

    lstm_seq<<<NWG, 256, 0, stream>>>(X, W_ih, W_hh, b_ih, b_hh, hbuf);
    lstm_head<<<1, 256, 0, stream>>>(hbuf, W_lin, b_lin, out);
}